// Round 1
// baseline (84.844 us; speedup 1.0000x reference)
//
#include <hip/hip_runtime.h>

#define DIM 512
#define TEMPERATURE 0.5f
#define EPS 1e-8f

// ws layout: ws[0..511] = s vector (sum of normalized rows), ws[512] = sum of ||n_i||^2
__global__ void init_ws_kernel(float* __restrict__ ws) {
    int t = threadIdx.x;
    if (t < DIM + 1) ws[t] = 0.0f;
}

// One wave (64 lanes) per row; each block (4 waves) covers 64 rows.
// Lane l holds row elements [4l,4l+4) and [256+4l, 256+4l+4) via two float4 loads
// (perfectly coalesced 16B/lane). Per-lane register accumulators across the
// block's rows; LDS combine across the 4 waves; one atomicAdd per s-element per block.
__global__ __launch_bounds__(256) void accum_kernel(const float* __restrict__ x,
                                                    float* __restrict__ ws, int N) {
    const int tid  = threadIdx.x;
    const int wave = tid >> 6;
    const int lane = tid & 63;
    const int rowBase = blockIdx.x * 64;

    float4 accA = make_float4(0.f, 0.f, 0.f, 0.f);
    float4 accB = make_float4(0.f, 0.f, 0.f, 0.f);
    float diag_acc = 0.f;

    for (int r = wave; r < 64; r += 4) {
        const int row = rowBase + r;
        if (row >= N) break;  // wave-uniform
        const float4* p = (const float4*)(x + (size_t)row * DIM);
        float4 a = p[lane];
        float4 b = p[lane + 64];

        float ss = a.x * a.x + a.y * a.y + a.z * a.z + a.w * a.w
                 + b.x * b.x + b.y * b.y + b.z * b.z + b.w * b.w;
        #pragma unroll
        for (int off = 1; off < 64; off <<= 1)
            ss += __shfl_xor(ss, off);

        const float inv = 1.0f / fmaxf(sqrtf(ss), EPS);
        if (lane == 0) diag_acc += ss * inv * inv;  // ||n_i||^2, once per row

        accA.x += a.x * inv; accA.y += a.y * inv; accA.z += a.z * inv; accA.w += a.w * inv;
        accB.x += b.x * inv; accB.y += b.y * inv; accB.z += b.z * inv; accB.w += b.w * inv;
    }

    __shared__ float sred[4][DIM];
    __shared__ float dred[4];
    float* myrow = sred[wave];
    myrow[lane * 4 + 0] = accA.x;
    myrow[lane * 4 + 1] = accA.y;
    myrow[lane * 4 + 2] = accA.z;
    myrow[lane * 4 + 3] = accA.w;
    myrow[256 + lane * 4 + 0] = accB.x;
    myrow[256 + lane * 4 + 1] = accB.y;
    myrow[256 + lane * 4 + 2] = accB.z;
    myrow[256 + lane * 4 + 3] = accB.w;
    if (lane == 0) dred[wave] = diag_acc;
    __syncthreads();

    #pragma unroll
    for (int idx = tid; idx < DIM; idx += 256) {
        float v = sred[0][idx] + sred[1][idx] + sred[2][idx] + sred[3][idx];
        atomicAdd(&ws[idx], v);
    }
    if (tid == 0) atomicAdd(&ws[DIM], dred[0] + dred[1] + dred[2] + dred[3]);
}

__global__ __launch_bounds__(256) void finalize_kernel(const float* __restrict__ ws,
                                                       float* __restrict__ out, int N) {
    const int tid = threadIdx.x;
    const float v0 = ws[tid];
    const float v1 = ws[tid + 256];
    float ss = v0 * v0 + v1 * v1;
    #pragma unroll
    for (int off = 1; off < 64; off <<= 1)
        ss += __shfl_xor(ss, off);

    __shared__ float wred[4];
    if ((tid & 63) == 0) wred[tid >> 6] = ss;
    __syncthreads();
    if (tid == 0) {
        const float total = wred[0] + wred[1] + wred[2] + wred[3];
        out[0] = (total - ws[DIM]) / (TEMPERATURE * (float)N);
    }
}

extern "C" void kernel_launch(void* const* d_in, const int* in_sizes, int n_in,
                              void* d_out, int out_size, void* d_ws, size_t ws_size,
                              hipStream_t stream) {
    const float* x = (const float*)d_in[0];
    float* ws = (float*)d_ws;
    float* out = (float*)d_out;
    const int N = in_sizes[0] / DIM;  // 16384

    init_ws_kernel<<<1, 576, 0, stream>>>(ws);
    const int blocks = (N + 63) / 64;  // 256
    accum_kernel<<<blocks, 256, 0, stream>>>(x, ws, N);
    finalize_kernel<<<1, 256, 0, stream>>>(ws, out, N);
}